// Round 3
// baseline (775.433 us; speedup 1.0000x reference)
//
#include <hip/hip_runtime.h>
#include <hip/hip_bf16.h>
#include <math.h>

#define D 128
#define EPS 1e-16f
#define K_SLOTS 4              // record slots per half-wave (chunk=49 rows spans <=2 segments)
#define REC_STRIDE 132         // floats: [0]=seg(int) [1]=m [2]=l [3]=pad [4..131]=a[128]
#define NBLK_A 2048
#define THR_A 256
#define NVW (NBLK_A * THR_A / 32)      // 16384 half-wave "virtual waves"
#define NREC (NVW * K_SLOTS)           // 65536 record slots

// ordered-uint encoding of float for atomicMax (monotone incl. negatives)
__device__ __forceinline__ unsigned f2o(float f) {
    unsigned u = __float_as_uint(f);
    return (u & 0x80000000u) ? ~u : (u | 0x80000000u);
}
__device__ __forceinline__ float o2f(unsigned o) {
    return (o & 0x80000000u) ? __uint_as_float(o & 0x7fffffffu) : __uint_as_float(~o);
}

// ---------------------------------------------------------------------------
// k_init: segMkey = ord(-inf); denomAcc = 0; outAcc = 0; record headers = -1.
// (d_ws is re-poisoned to 0xAA before every timed launch.)
// ---------------------------------------------------------------------------
__global__ void k_init(unsigned* __restrict__ segMkey, float* __restrict__ denomAcc,
                       float* __restrict__ outAcc, float* __restrict__ recs, int S) {
    const int t = blockIdx.x * blockDim.x + threadIdx.x;
    const int stride = gridDim.x * blockDim.x;
    for (int i = t; i < S; i += stride) { segMkey[i] = 0x007FFFFFu; denomAcc[i] = 0.f; }
    for (int i = t; i < S * D; i += stride) outAcc[i] = 0.f;
    for (int r = t; r < NREC; r += stride) ((int*)recs)[(size_t)r * REC_STRIDE] = -1;
}

// ---------------------------------------------------------------------------
// Kernel A: single pass over x. Each 32-lane HALF-wave owns a contiguous row
// chunk. Per row: float4 load (1KiB per wave-instruction), dot with W frag,
// 5-step shuffle reduce (sum is uniform within the half — no broadcast),
// online-softmax update of (m,l,acc[float4/lane]). Depth-2 software pipeline
// on x and batch. Flush {seg,m,l,a[128]} records on segment change / end.
// ---------------------------------------------------------------------------
__global__ __launch_bounds__(256) void k_fused(const float* __restrict__ x,
        const int* __restrict__ batch,
        const float* __restrict__ W,
        const float* __restrict__ bptr,
        float* __restrict__ gate,
        float* __restrict__ recs,
        int N, int chunk) {
    const int sub = threadIdx.x & 31;                       // lane within half
    const int v   = (blockIdx.x * blockDim.x + threadIdx.x) >> 5;
    const int i0  = v * chunk;
    const int i1  = min(N, i0 + chunk);
    if (i0 >= i1) return;
    float* myrec = recs + (size_t)v * K_SLOTS * REC_STRIDE;

    const float4 w  = ((const float4*)W)[sub];
    const float bias = bptr[0];

    float4 acc = make_float4(0.f, 0.f, 0.f, 0.f);
    float m = -INFINITY, l = 0.f;
    int cur = batch[i0];
    int cnt = 0;

    auto flush = [&]() {
        float* r = myrec + min(cnt, K_SLOTS - 1) * REC_STRIDE;
        if (sub == 0) { ((int*)r)[0] = cur; r[1] = m; r[2] = l; }
        ((float4*)(r + 4))[sub] = acc;
        ++cnt;
        acc = make_float4(0.f, 0.f, 0.f, 0.f); m = -INFINITY; l = 0.f;
    };

    const int n = i1 - i0;
    // depth-2 pipeline
    float4 xc = ((const float4*)(x + (size_t)i0 * D))[sub];
    int bc = cur;
    float4 xn = make_float4(0.f, 0.f, 0.f, 0.f);
    int bn = cur;
    if (n > 1) {
        xn = ((const float4*)(x + (size_t)(i0 + 1) * D))[sub];
        bn = batch[i0 + 1];
    }

    for (int s = 0; s < n; ++s) {
        float4 x2 = xn; int b2 = bn;
        if (s + 2 < n) {
            x2 = ((const float4*)(x + (size_t)(i0 + s + 2) * D))[sub];
            b2 = batch[i0 + s + 2];
        }
        float p = xc.x * w.x + xc.y * w.y + xc.z * w.z + xc.w * w.w;
        p += __shfl_xor(p, 1);
        p += __shfl_xor(p, 2);
        p += __shfl_xor(p, 4);
        p += __shfl_xor(p, 8);
        p += __shfl_xor(p, 16);
        const float g = p + bias;                 // uniform within half
        if (sub == 0) gate[i0 + s] = g;

        if (bc != cur) { flush(); cur = bc; }
        if (g > m) {
            const float sc = __expf(m - g);       // first row: exp(-inf)=0
            l = l * sc + 1.f;
            acc.x = acc.x * sc + xc.x;
            acc.y = acc.y * sc + xc.y;
            acc.z = acc.z * sc + xc.z;
            acc.w = acc.w * sc + xc.w;
            m = g;
        } else {
            const float e = __expf(g - m);
            l += e;
            acc.x += e * xc.x;
            acc.y += e * xc.y;
            acc.z += e * xc.z;
            acc.w += e * xc.w;
        }
        xc = xn; bc = bn; xn = x2; bn = b2;
    }
    flush();
}

// ---------------------------------------------------------------------------
// B1: per-segment running max over records via atomicMax on ordered uints.
// ---------------------------------------------------------------------------
__global__ void k_max(const float* __restrict__ recs, unsigned* __restrict__ segMkey) {
    const int t = blockIdx.x * blockDim.x + threadIdx.x;
    const int stride = gridDim.x * blockDim.x;
    for (int r = t; r < NREC; r += stride) {
        const float* rec = recs + (size_t)r * REC_STRIDE;
        const int seg = ((const int*)rec)[0];
        if (seg >= 0) atomicMax(&segMkey[seg], f2o(rec[1]));
    }
}

// ---------------------------------------------------------------------------
// B2: one wave per record: sc=exp(m-M); denomAcc[s]+=sc*l; outAcc[s,:]+=sc*a.
// ---------------------------------------------------------------------------
__global__ void k_acc(const float* __restrict__ recs,
                      const unsigned* __restrict__ segMkey,
                      float* __restrict__ denomAcc, float* __restrict__ outAcc) {
    const int lane = threadIdx.x & 63;
    const int wid  = (blockIdx.x * blockDim.x + threadIdx.x) >> 6;
    const int nw   = (gridDim.x * blockDim.x) >> 6;
    for (int r = wid; r < NREC; r += nw) {
        const float* rec = recs + (size_t)r * REC_STRIDE;
        const int seg = ((const int*)rec)[0];
        if (seg < 0) continue;
        const float sc = __expf(rec[1] - o2f(segMkey[seg]));
        if (lane == 0) atomicAdd(&denomAcc[seg], sc * rec[2]);
        const float2 a = ((const float2*)(rec + 4))[lane];
        atomicAdd(&outAcc[(size_t)seg * D + 2 * lane],     sc * a.x);
        atomicAdd(&outAcc[(size_t)seg * D + 2 * lane + 1], sc * a.y);
    }
}

// ---------------------------------------------------------------------------
// B3: out[s][j] = outAcc[s][j] / (denom[s] + EPS)
// ---------------------------------------------------------------------------
__global__ void k_fin(const float* __restrict__ outAcc, const float* __restrict__ denomAcc,
                      float* __restrict__ out, int SD) {
    const int t = blockIdx.x * blockDim.x + threadIdx.x;
    if (t < SD) out[t] = outAcc[t] / (denomAcc[t >> 7] + EPS);
}

// ---------------------------------------------------------------------------
// C: gate_sm[i] = exp(gate[i] - M[b]) / (denom[b] + EPS)
// ---------------------------------------------------------------------------
__global__ void k_gatesm(const float* __restrict__ gate,
                         const int* __restrict__ batch,
                         const unsigned* __restrict__ segMkey,
                         const float* __restrict__ denomAcc,
                         float* __restrict__ gate_sm, int N) {
    int i = blockIdx.x * blockDim.x + threadIdx.x;
    const int stride = gridDim.x * blockDim.x;
    for (; i < N; i += stride) {
        const int b = batch[i];
        gate_sm[i] = __expf(gate[i] - o2f(segMkey[b])) / (denomAcc[b] + EPS);
    }
}

extern "C" void kernel_launch(void* const* d_in, const int* in_sizes, int n_in,
                              void* d_out, int out_size, void* d_ws, size_t ws_size,
                              hipStream_t stream) {
    const float* x      = (const float*)d_in[0];
    const int*   batch  = (const int*)d_in[1];
    const float* gate_W = (const float*)d_in[3];
    const float* gate_b = (const float*)d_in[4];

    const int N = in_sizes[0] / D;
    const int S = (out_size - N) / D;          // out layout: [S*D pooled | N gate_sm]

    float* out     = (float*)d_out;
    float* gate_sm = (float*)d_out + (size_t)S * D;

    float*    gate     = (float*)d_ws;                 // [N]
    unsigned* segMkey  = (unsigned*)(gate + N);        // [S]
    float*    denomAcc = (float*)(segMkey + S);        // [S]
    float*    outAcc   = denomAcc + S;                 // [S*D]
    size_t off = ((size_t)(N + 2 * S + S * D) + 3) & ~(size_t)3;
    float*    recs     = (float*)d_ws + off;           // [NREC, REC_STRIDE]

    int chunk = (N + NVW - 1) / NVW;                   // 49 for N=800000

    k_init<<<64, 256, 0, stream>>>(segMkey, denomAcc, outAcc, recs, S);
    k_fused<<<NBLK_A, THR_A, 0, stream>>>(x, batch, gate_W, gate_b, gate, recs, N, chunk);
    k_max<<<256, 256, 0, stream>>>(recs, segMkey);
    k_acc<<<1024, 256, 0, stream>>>(recs, segMkey, denomAcc, outAcc);
    k_fin<<<(S * D + 255) / 256, 256, 0, stream>>>(outAcc, denomAcc, out, S * D);
    k_gatesm<<<512, 256, 0, stream>>>(gate, batch, segMkey, denomAcc, gate_sm, N);
}

// Round 4
// 628.537 us; speedup vs baseline: 1.2337x; 1.2337x over previous
//
#include <hip/hip_runtime.h>
#include <hip/hip_bf16.h>
#include <math.h>

#define D 128
#define EPS 1e-16f
#define K_SLOTS 4              // records per wave chunk (chunk=98 rows spans <=2 of 64 ~12.5k-row segments)
#define REC_STRIDE 132         // floats: [0]=seg(int) [1]=m [2]=l [3]=pad [4..131]=a[128]
#define NBLK_A 2048
#define THR_A 256
#define NWV (NBLK_A * THR_A / 64)   // 8192 waves
#define NREC (NWV * K_SLOTS)        // 32768 record slots
#define NBLK_R 256
#define RB (NREC / NBLK_R)          // 128 slots per reduce block

// ordered-uint encoding of float for atomicMax (monotone incl. negatives)
__device__ __forceinline__ unsigned f2o(float f) {
    unsigned u = __float_as_uint(f);
    return (u & 0x80000000u) ? ~u : (u | 0x80000000u);
}
__device__ __forceinline__ float o2f(unsigned o) {
    return (o & 0x80000000u) ? __uint_as_float(o & 0x7fffffffu) : __uint_as_float(~o);
}
__device__ __forceinline__ float bcast0(float v) {   // SALU broadcast of a value uniform-in-half0
    return __uint_as_float(__builtin_amdgcn_readfirstlane(__float_as_uint(v)));
}

// ---------------------------------------------------------------------------
// k_init: segMkey=ord(-inf), denomAcc=0, outAcc=0, record headers=-1.
// ---------------------------------------------------------------------------
__global__ void k_init(unsigned* __restrict__ segMkey, float* __restrict__ denomAcc,
                       float* __restrict__ outAcc, float* __restrict__ recs, int S) {
    const int t = blockIdx.x * blockDim.x + threadIdx.x;
    const int stride = gridDim.x * blockDim.x;
    for (int i = t; i < S; i += stride) { segMkey[i] = 0x007FFFFFu; denomAcc[i] = 0.f; }
    for (int i = t; i < S * D; i += stride) outAcc[i] = 0.f;
    for (int r = t; r < NREC; r += stride) ((int*)recs)[(size_t)r * REC_STRIDE] = -1;
}

// ---------------------------------------------------------------------------
// Kernel A: one WAVE per contiguous row chunk, TWO rows per iteration.
// Lanes 0-31 hold row i (float4/lane), lanes 32-63 hold row i+1 — a single
// contiguous 1KiB load. One shared 5-step xor butterfly reduces both rows'
// gate dots at once; g0/g1 extracted via shfl_xor(32)+readfirstlane so ALL
// control flow (softmax update, segment flush) is wave-uniform. Online
// softmax state (m,l) scalar; acc float4/lane (halves summed at flush).
// Flush writes a {seg,m,l,a[128]} record and atomicMax's the segment max.
// ---------------------------------------------------------------------------
__global__ __launch_bounds__(256) void k_fused(const float* __restrict__ x,
        const int* __restrict__ batch,
        const float* __restrict__ W,
        const float* __restrict__ bptr,
        float* __restrict__ gate,
        float* __restrict__ recs,
        unsigned* __restrict__ segMkey,
        int N, int chunk) {
    const int lane = threadIdx.x & 63;
    const int sub  = lane & 31;
    const int h    = lane >> 5;
    const int wv   = (blockIdx.x * blockDim.x + threadIdx.x) >> 6;
    const int i0   = wv * chunk;
    const int i1   = min(N, i0 + chunk);
    if (i0 >= i1) return;
    float* myrec = recs + (size_t)wv * K_SLOTS * REC_STRIDE;

    const float4 w = ((const float4*)W)[sub];
    const float bias = bptr[0];

    float4 acc = make_float4(0.f, 0.f, 0.f, 0.f);
    float m = -INFINITY, l = 0.f;
    int cur = batch[i0];
    int cnt = 0;

    auto flush = [&]() {
        // combine the two half-accumulators (same columns, different rows)
        acc.x += __shfl_xor(acc.x, 32);
        acc.y += __shfl_xor(acc.y, 32);
        acc.z += __shfl_xor(acc.z, 32);
        acc.w += __shfl_xor(acc.w, 32);
        float* r = myrec + min(cnt, K_SLOTS - 1) * REC_STRIDE;
        if (lane == 0) { ((int*)r)[0] = cur; r[1] = m; r[2] = l; }
        if (h == 0) ((float4*)(r + 4))[sub] = acc;
        if (lane == 0) atomicMax(&segMkey[cur], f2o(m));
        ++cnt;
        acc = make_float4(0.f, 0.f, 0.f, 0.f); m = -INFINITY; l = 0.f;
    };

    // single-row update (rare slow path / tail). Row lives in half hr's lanes.
    auto one = [&](int b, float gs, int hr, float4 xv) {
        if (b != cur) { flush(); cur = b; }
        const float m2 = fmaxf(m, gs);
        const float s  = __expf(m - m2);
        const float e  = __expf(gs - m2);
        l = l * s + e;
        const float es = (h == hr) ? e : 0.f;
        acc.x = acc.x * s + es * xv.x;
        acc.y = acc.y * s + es * xv.y;
        acc.z = acc.z * s + es * xv.z;
        acc.w = acc.w * s + es * xv.w;
        m = m2;
    };

    const int n = i1 - i0;
    const int npair = n >> 1;

    if (npair > 0) {
        // depth-2 software pipeline on the 1KiB pair-load and batch pair
        float4 xc = ((const float4*)(x + (size_t)i0 * D))[lane];
        int b0c = batch[i0], b1c = batch[i0 + 1];
        float4 xn = xc; int b0n = b0c, b1n = b1c;
        if (npair > 1) {
            xn = ((const float4*)(x + (size_t)(i0 + 2) * D))[lane];
            b0n = batch[i0 + 2]; b1n = batch[i0 + 3];
        }
        for (int p = 0; p < npair; ++p) {
            float4 x2 = xn; int b02 = b0n, b12 = b1n;
            if (p + 2 < npair) {
                const int ir = i0 + 2 * (p + 2);
                x2 = ((const float4*)(x + (size_t)ir * D))[lane];
                b02 = batch[ir]; b12 = batch[ir + 1];
            }
            const int i = i0 + 2 * p;
            // both rows' gate dots in one butterfly
            float pd = xc.x * w.x + xc.y * w.y + xc.z * w.z + xc.w * w.w;
            pd += __shfl_xor(pd, 1);
            pd += __shfl_xor(pd, 2);
            pd += __shfl_xor(pd, 4);
            pd += __shfl_xor(pd, 8);
            pd += __shfl_xor(pd, 16);
            const float g  = pd + bias;              // lane's own row's gate
            const float go = __shfl_xor(g, 32);      // other half's gate
            const float g0 = bcast0(g);              // row i   (scalar)
            const float g1 = bcast0(go);             // row i+1 (scalar)
            if (sub == 0) gate[i + h] = g;           // lanes 0 & 32 store

            if (b0c == cur && b1c == cur) {          // uniform fast path, branchless math
                const float m2 = fmaxf(fmaxf(m, g0), g1);
                const float s  = __expf(m - m2);
                const float e  = __expf(g - m2);     // per-lane: its row's weight
                l = l * s + __expf(g0 - m2) + __expf(g1 - m2);
                acc.x = acc.x * s + e * xc.x;
                acc.y = acc.y * s + e * xc.y;
                acc.z = acc.z * s + e * xc.z;
                acc.w = acc.w * s + e * xc.w;
                m = m2;
            } else {                                 // rare, still wave-uniform
                one(b0c, g0, 0, xc);
                one(b1c, g1, 1, xc);
            }
            xc = xn; b0c = b0n; b1c = b1n;
            xn = x2; b0n = b02; b1n = b12;
        }
    }
    if (n & 1) {                                     // odd tail row (not hit for N=800000)
        const int i = i1 - 1;
        float4 xt = ((const float4*)(x + (size_t)i * D))[sub];   // both halves load same row
        float pd = xt.x * w.x + xt.y * w.y + xt.z * w.z + xt.w * w.w;
        pd += __shfl_xor(pd, 1);
        pd += __shfl_xor(pd, 2);
        pd += __shfl_xor(pd, 4);
        pd += __shfl_xor(pd, 8);
        pd += __shfl_xor(pd, 16);
        const float gs = bcast0(pd + bias);
        if (lane == 0) gate[i] = gs;
        one(batch[i], gs, 0, xt);                    // half1 contributes 0
    }
    flush();
}

// ---------------------------------------------------------------------------
// k_acc: block-sequential record sweep. Block b owns slots [b*RB, (b+1)*RB)
// (slot order follows chunk order -> segment mostly nondecreasing). Thread j
// (0..127) holds column j's accumulator in a register; flush to outAcc via
// one atomicAdd per thread on segment change (~2 flushes/block).
// ---------------------------------------------------------------------------
__global__ __launch_bounds__(128) void k_acc(const float* __restrict__ recs,
        const unsigned* __restrict__ segMkey,
        float* __restrict__ denomAcc, float* __restrict__ outAcc) {
    const int j  = threadIdx.x;
    const int r0 = blockIdx.x * RB;
    float a = 0.f, dl = 0.f;
    int curseg = -1;
    for (int r = r0; r < r0 + RB; ++r) {
        const float* rec = recs + (size_t)r * REC_STRIDE;
        const int seg = ((const int*)rec)[0];
        if (seg < 0) continue;
        if (seg != curseg) {
            if (curseg >= 0) {
                atomicAdd(&outAcc[(size_t)curseg * D + j], a);
                if (j == 0) atomicAdd(&denomAcc[curseg], dl);
            }
            curseg = seg; a = 0.f; dl = 0.f;
        }
        const float sc = __expf(rec[1] - o2f(segMkey[seg]));
        a += sc * rec[4 + j];
        if (j == 0) dl += sc * rec[2];
    }
    if (curseg >= 0) {
        atomicAdd(&outAcc[(size_t)curseg * D + j], a);
        if (j == 0) atomicAdd(&denomAcc[curseg], dl);
    }
}

// ---------------------------------------------------------------------------
// k_final: out[s][j] = outAcc/(denom+EPS); gate_sm[i] = exp(g-M[b])/(denom[b]+EPS)
// ---------------------------------------------------------------------------
__global__ void k_final(const float* __restrict__ gate,
                        const int* __restrict__ batch,
                        const unsigned* __restrict__ segMkey,
                        const float* __restrict__ denomAcc,
                        const float* __restrict__ outAcc,
                        float* __restrict__ out, float* __restrict__ gate_sm,
                        int N, int SD) {
    const int t = blockIdx.x * blockDim.x + threadIdx.x;
    if (t < SD) out[t] = outAcc[t] / (denomAcc[t >> 7] + EPS);
    const int stride = gridDim.x * blockDim.x;
    for (int i = t; i < N; i += stride) {
        const int b = batch[i];
        gate_sm[i] = __expf(gate[i] - o2f(segMkey[b])) / (denomAcc[b] + EPS);
    }
}

extern "C" void kernel_launch(void* const* d_in, const int* in_sizes, int n_in,
                              void* d_out, int out_size, void* d_ws, size_t ws_size,
                              hipStream_t stream) {
    const float* x      = (const float*)d_in[0];
    const int*   batch  = (const int*)d_in[1];
    const float* gate_W = (const float*)d_in[3];
    const float* gate_b = (const float*)d_in[4];

    const int N = in_sizes[0] / D;
    const int S = (out_size - N) / D;          // out layout: [S*D pooled | N gate_sm]

    float* out     = (float*)d_out;
    float* gate_sm = (float*)d_out + (size_t)S * D;

    float*    gate     = (float*)d_ws;                 // [N]
    unsigned* segMkey  = (unsigned*)(gate + N);        // [S]
    float*    denomAcc = (float*)(segMkey + S);        // [S]
    float*    outAcc   = denomAcc + S;                 // [S*D]
    size_t off = ((size_t)(N + 2 * S + S * D) + 3) & ~(size_t)3;   // 16B-align records
    float*    recs     = (float*)d_ws + off;           // [NREC, REC_STRIDE]

    int chunk = (N + NWV - 1) / NWV;                   // 98 for N=800000
    chunk = (chunk + 1) & ~1;                          // even -> rows pair cleanly

    k_init<<<128, 256, 0, stream>>>(segMkey, denomAcc, outAcc, recs, S);
    k_fused<<<NBLK_A, THR_A, 0, stream>>>(x, batch, gate_W, gate_b, gate, recs, segMkey, N, chunk);
    k_acc<<<NBLK_R, 128, 0, stream>>>(recs, segMkey, denomAcc, outAcc);
    k_final<<<1024, 256, 0, stream>>>(gate, batch, segMkey, denomAcc, outAcc, out, gate_sm, N, S * D);
}